// Round 2
// baseline (235.071 us; speedup 1.0000x reference)
//
#include <hip/hip_runtime.h>
#include <hip/hip_bf16.h>
#include <stdint.h>

// KipfMLPGNN: B=32 batches, N=64 nodes, D=128 embd, H=256 hidden, L=3 layers.
// Factorization: first MLP layer split into per-node sender/receiver halves,
// precomputed per node (k_T, bf16). Per-edge work = relu(add) + H->D GEMM via
// MFMA. k_edge: one block per (b,r), 32KB LDS h-buffer shared by both MLPs
// sequentially (5 blocks/CU occupancy).

#define NB 32
#define NN 64
#define DD 128
#define HH 256

typedef __attribute__((ext_vector_type(4))) float f32x4;
typedef __attribute__((ext_vector_type(4))) uint32_t u32x4;
typedef __attribute__((ext_vector_type(8))) __bf16 bf16x8;

__device__ __forceinline__ uint16_t f2bf(float x) {
  uint32_t u = __builtin_bit_cast(uint32_t, x);
  u += 0x7fffu + ((u >> 16) & 1u);   // RNE
  return (uint16_t)(u >> 16);
}
__device__ __forceinline__ float bf_lo(uint32_t u) {
  return __builtin_bit_cast(float, u << 16);
}
__device__ __forceinline__ float bf_hi(uint32_t u) {
  return __builtin_bit_cast(float, u & 0xffff0000u);
}

// E[node][d] = table[x[node]][d]    (2048 nodes x 128 f32, via float4)
__global__ __launch_bounds__(256) void k_gather(const int* __restrict__ x,
                                                const float* __restrict__ table,
                                                float* __restrict__ E) {
  int i = blockIdx.x * 256 + threadIdx.x;     // 0..65535 float4 slots
  int node = i >> 5;
  ((f32x4*)E)[i] = ((const f32x4*)table)[(size_t)x[node] * 32 + (i & 31)];
}

// Wt[g][k][h]: g0=W1_0 sender half, g1=W1_0 receiver half, g2/g3 = W1_1 halves
// W2bf[2][d][h]: bf16 copies of W2_0 / W2_1 (row-major, h contiguous).
__global__ __launch_bounds__(256) void k_prep(const float* __restrict__ W1_0,
                                              const float* __restrict__ W1_1,
                                              const float* __restrict__ W2_0,
                                              const float* __restrict__ W2_1,
                                              float* __restrict__ Wt,
                                              uint16_t* __restrict__ W2bf) {
  int tid = blockIdx.x * 256 + threadIdx.x;   // 65536 threads
  for (int idx = tid; idx < 4 * 128 * 256; idx += 65536) {
    int g = idx >> 15, k = (idx >> 8) & 127, h = idx & 255;
    const float* W = (g < 2) ? W1_0 : W1_1;
    Wt[idx] = W[h * 256 + (g & 1) * 128 + k];
  }
  if (tid < 32768) {
    W2bf[tid]         = f2bf(W2_0[tid]);
    W2bf[32768 + tid] = f2bf(W2_1[tid]);
  }
}

// Tall[node][1024] = [Ts0 | Tr0+b1_0 | Ts1 | Tr1+b1_1]   (bf16, per layer)
// Block: 16 nodes, 256 threads; thread t owns column h=t of all 4 groups.
__global__ __launch_bounds__(256) void k_T(const float* __restrict__ E,
                                           const float* __restrict__ Wt,
                                           const float* __restrict__ b1_0,
                                           const float* __restrict__ b1_1,
                                           uint16_t* __restrict__ Tall) {
  __shared__ float Els[16 * 128];
  int t = threadIdx.x;
  int node0 = blockIdx.x * 16;
  ((f32x4*)Els)[t]       = ((const f32x4*)(E + (size_t)node0 * 128))[t];
  ((f32x4*)Els)[t + 256] = ((const f32x4*)(E + (size_t)node0 * 128))[t + 256];
  __syncthreads();
  float acc[4][16];
#pragma unroll
  for (int g = 0; g < 4; ++g)
#pragma unroll
    for (int m = 0; m < 16; ++m) acc[g][m] = 0.f;
#pragma unroll 2
  for (int k = 0; k < 128; ++k) {
    float w0 = Wt[(0 * 128 + k) * 256 + t];
    float w1 = Wt[(1 * 128 + k) * 256 + t];
    float w2 = Wt[(2 * 128 + k) * 256 + t];
    float w3 = Wt[(3 * 128 + k) * 256 + t];
#pragma unroll
    for (int m = 0; m < 16; ++m) {
      float e = Els[m * 128 + k];      // broadcast read
      acc[0][m] = fmaf(e, w0, acc[0][m]);
      acc[1][m] = fmaf(e, w1, acc[1][m]);
      acc[2][m] = fmaf(e, w2, acc[2][m]);
      acc[3][m] = fmaf(e, w3, acc[3][m]);
    }
  }
  float bias1 = b1_0[t], bias3 = b1_1[t];
#pragma unroll
  for (int m = 0; m < 16; ++m) {
    uint16_t* row = Tall + (size_t)(node0 + m) * 1024;
    row[0 * 256 + t] = f2bf(acc[0][m]);
    row[1 * 256 + t] = f2bf(acc[1][m] + bias1);
    row[2 * 256 + t] = f2bf(acc[2][m]);
    row[3 * 256 + t] = f2bf(acc[3][m] + bias3);
  }
}

// One block per (b, r). For each MLP p in {0,1}: stage h[c][k] =
// relu(Ts[c][k] + Tr[r][k]) to 32KB LDS as bf16 (XOR swizzle (c&7)<<4), then
// 64x256 @ 256x128 MFMA. Epilogue blends by arc and reduces over c.
__global__ __launch_bounds__(256) void k_edge(const uint16_t* __restrict__ Tall,
                                              const int* __restrict__ arcs,
                                              const float* E,
                                              float* out,
                                              const uint16_t* __restrict__ W2bf,
                                              const float* __restrict__ b2_0,
                                              const float* __restrict__ b2_1,
                                              int last) {
  __shared__ uint16_t hl[NN * HH];   // 32 KB, reused by both MLPs
  int t = threadIdx.x;
  int b = blockIdx.y;
  int r = last ? 0 : blockIdx.x;
  const uint16_t* Tb = Tall + (size_t)b * NN * 1024;

  int lane = t & 63;
  int w = t >> 6;            // wave id: owns N columns [w*32, w*32+32)
  int col = lane & 15;
  int khi = lane >> 4;
  int sc = t >> 2;                 // staging row
  int skb = (t & 3) * 64;          // staging k-base
  int sswz = (sc & 7) << 4;
  char* sdst = (char*)hl + sc * 512;

  f32x4 acc[2][4][2];
  const f32x4 z = {0.f, 0.f, 0.f, 0.f};
#pragma unroll
  for (int p = 0; p < 2; ++p)
#pragma unroll
    for (int mt = 0; mt < 4; ++mt)
#pragma unroll
      for (int nt = 0; nt < 2; ++nt) acc[p][mt][nt] = z;

#pragma unroll
  for (int p = 0; p < 2; ++p) {
    // ---- stage h_p ----
    const uint16_t* tsp = Tb + sc * 1024 + p * 512;
    const uint16_t* trp = Tb + r * 1024 + p * 512 + 256;
#pragma unroll
    for (int j = 0; j < 8; ++j) {
      int k = skb + j * 8;
      u32x4 us = *(const u32x4*)(tsp + k);
      u32x4 ur = *(const u32x4*)(trp + k);
      u32x4 o;
#pragma unroll
      for (int ii = 0; ii < 4; ++ii) {
        float lo = fmaxf(bf_lo(us[ii]) + bf_lo(ur[ii]), 0.f);
        float hi = fmaxf(bf_hi(us[ii]) + bf_hi(ur[ii]), 0.f);
        o[ii] = (uint32_t)f2bf(lo) | ((uint32_t)f2bf(hi) << 16);
      }
      *(u32x4*)(sdst + (((k * 2) ^ sswz))) = o;
    }
    __syncthreads();

    // ---- MFMA: h_p (64x256) @ W2_p^T (256x128), this wave's 32 N-cols ----
    const uint16_t* w2p = W2bf + p * 32768;
#pragma unroll
    for (int ks = 0; ks < 8; ++ks) {
      int k0 = ks * 32 + khi * 8;
      bf16x8 a[4];
#pragma unroll
      for (int mt = 0; mt < 4; ++mt) {
        int cc = mt * 16 + col;
        int off = cc * 512 + ((k0 * 2) ^ ((cc & 7) << 4));
        a[mt] = *(const bf16x8*)((const char*)hl + off);
      }
      bf16x8 bv[2];
#pragma unroll
      for (int nt = 0; nt < 2; ++nt) {
        int n = w * 32 + nt * 16 + col;
        bv[nt] = *(const bf16x8*)(const void*)(w2p + n * HH + k0);
      }
#pragma unroll
      for (int mt = 0; mt < 4; ++mt)
#pragma unroll
        for (int nt = 0; nt < 2; ++nt)
          acc[p][mt][nt] = __builtin_amdgcn_mfma_f32_16x16x32_bf16(
              a[mt], bv[nt], acc[p][mt][nt], 0, 0, 0);
    }
    if (p == 0) __syncthreads();   // protect hl before restaging
  }

  // epilogue: bias, relu, arc blend, reduce over c (rows)
  int d0 = w * 32 + col;
  int d1 = d0 + 16;
  float bb0[2] = {b2_0[d0], b2_0[d1]};
  float bb1[2] = {b2_1[d0], b2_1[d1]};
  const int* arow = arcs + ((size_t)b * NN + r) * NN;
  float sum0 = 0.f, sum1 = 0.f;
#pragma unroll
  for (int mt = 0; mt < 4; ++mt) {
#pragma unroll
    for (int j = 0; j < 4; ++j) {
      int cc = mt * 16 + khi * 4 + j;
      float af = (float)arow[cc];   // 0 or 1
      {
        float m0 = fmaxf(acc[0][mt][0][j] + bb0[0], 0.f);
        float m1 = fmaxf(acc[1][mt][0][j] + bb1[0], 0.f);
        sum0 += m0 + af * (m1 - m0);
      }
      {
        float m0 = fmaxf(acc[0][mt][1][j] + bb0[1], 0.f);
        float m1 = fmaxf(acc[1][mt][1][j] + bb1[1], 0.f);
        sum1 += m0 + af * (m1 - m0);
      }
    }
  }
  sum0 += __shfl_xor(sum0, 16);
  sum0 += __shfl_xor(sum0, 32);
  sum1 += __shfl_xor(sum1, 16);
  sum1 += __shfl_xor(sum1, 32);
  if (lane < 16) {
    if (last) {
      size_t base = (size_t)b * NN * DD;   // row r=0
      out[b * DD + d0] = E[base + d0] + sum0;
      out[b * DD + d1] = E[base + d1] + sum1;
    } else {
      size_t base = ((size_t)b * NN + r) * DD;
      out[base + d0] = E[base + d0] + sum0;
      out[base + d1] = E[base + d1] + sum1;
    }
  }
}

extern "C" void kernel_launch(void* const* d_in, const int* in_sizes, int n_in,
                              void* d_out, int out_size, void* d_ws, size_t ws_size,
                              hipStream_t stream) {
  const int* x       = (const int*)d_in[0];
  const int* arcs    = (const int*)d_in[1];
  const float* table = (const float*)d_in[3];
  const float* W1_0  = (const float*)d_in[4];
  const float* b1_0  = (const float*)d_in[5];
  const float* W2_0  = (const float*)d_in[6];
  const float* b2_0  = (const float*)d_in[7];
  const float* W1_1  = (const float*)d_in[8];
  const float* b1_1  = (const float*)d_in[9];
  const float* W2_1  = (const float*)d_in[10];
  const float* b2_1  = (const float*)d_in[11];
  float* out = (float*)d_out;

  char* ws = (char*)d_ws;
  float* E        = (float*)ws;                                   // 1 MB
  uint16_t* Tall  = (uint16_t*)(ws + (1u << 20));                 // 4 MB
  float* Wt       = (float*)(ws + (5u << 20));                    // 512 KB
  uint16_t* W2bf  = (uint16_t*)(ws + (5u << 20) + (512u << 10));  // 128 KB

  k_gather<<<256, 256, 0, stream>>>(x, table, E);
  k_prep<<<256, 256, 0, stream>>>(W1_0, W1_1, W2_0, W2_1, Wt, W2bf);
  for (int l = 0; l < 3; ++l) {
    int last = (l == 2);
    k_T<<<128, 256, 0, stream>>>(E, Wt, b1_0, b1_1, Tall);
    dim3 grid(last ? 1 : NN, NB);
    k_edge<<<grid, 256, 0, stream>>>(Tall, arcs, E, last ? out : E,
                                     W2bf, b2_0, b2_1, last);
  }
}

// Round 3
// 229.443 us; speedup vs baseline: 1.0245x; 1.0245x over previous
//
#include <hip/hip_runtime.h>
#include <hip/hip_bf16.h>
#include <stdint.h>

// KipfMLPGNN: B=32, N=64 nodes, D=128, H=256, L=3 layers.
// Factorizations:
//  - First MLP layer split into per-node sender/receiver halves (k_T, fp16).
//  - Arc blend separates: agg = Sum_c (1-a)*m0 + Sum_c a*m1 -> two phases.
// k_edge: block=(b, 8 r's), h built in registers (v_pk_add/max_f16), only W2
// in LDS (64KB/phase, swizzled), partial sums in registers, no r-loop barriers.

#define NB 32
#define NN 64
#define DD 128
#define HH 256

typedef __attribute__((ext_vector_type(4))) float f32x4;
typedef __attribute__((ext_vector_type(4))) uint32_t u32x4;
typedef __attribute__((ext_vector_type(8))) _Float16 f16x8;

__device__ __forceinline__ uint64_t cvt4h(f32x4 v) {
  union { _Float16 h[4]; uint64_t u; } x;
  x.h[0] = (_Float16)v[0]; x.h[1] = (_Float16)v[1];
  x.h[2] = (_Float16)v[2]; x.h[3] = (_Float16)v[3];
  return x.u;
}

// E[node][d] = table[x[node]][d]  (2048 x 128 f32)
__global__ __launch_bounds__(256) void k_gather(const int* __restrict__ x,
                                                const float* __restrict__ table,
                                                float* __restrict__ E) {
  int i = blockIdx.x * 256 + threadIdx.x;
  int node = i >> 5;
  ((f32x4*)E)[i] = ((const f32x4*)table)[(size_t)x[node] * 32 + (i & 31)];
}

// W1fp[2][256h][256in] fp16 (natural layout), W2fp[2][128d][256h] fp16.
__global__ __launch_bounds__(256) void k_prep(const float* __restrict__ W1_0,
                                              const float* __restrict__ W1_1,
                                              const float* __restrict__ W2_0,
                                              const float* __restrict__ W2_1,
                                              _Float16* __restrict__ W1fp,
                                              _Float16* __restrict__ W2fp) {
  int tid = blockIdx.x * 256 + threadIdx.x;   // 192*256 = 49152 f32x4 chunks
  const float* src; uint64_t* dst; int off;
  if (tid < 32768) {
    src = (tid < 16384) ? W1_0 : W1_1;
    off = tid & 16383;
    dst = (uint64_t*)W1fp + (tid >> 14) * 16384 + off;
  } else {
    int t2 = tid - 32768;
    src = (t2 < 8192) ? W2_0 : W2_1;
    off = t2 & 8191;
    dst = (uint64_t*)W2fp + (t2 >> 13) * 8192 + off;
  }
  *dst = cvt4h(((const f32x4*)src)[off]);
}

// Tfp[node][1024] = [Ts0 | Tr0+b1_0 | Ts1 | Tr1+b1_1]  (fp16)
// grid (8, 32): x = q*2+half (q in {Ts0,Tr0,Ts1,Tr1}, 128 h-cols), y = 64-node blk
__global__ __launch_bounds__(256) void k_T(const float* __restrict__ E,
                                           const _Float16* __restrict__ W1fp,
                                           const float* __restrict__ b1_0,
                                           const float* __restrict__ b1_1,
                                           _Float16* __restrict__ Tfp) {
  __shared__ char Els[64 * 256];     // 64 nodes x 128 f16, swizzled rows (256B)
  int t = threadIdx.x;
  int gi = blockIdx.x;
  int q = gi >> 1;                   // group 0..3
  int hb = (gi & 1) * 128;           // h-half
  int inoff = (q & 1) * 128;         // sender(0) / receiver(128) input half
  int node0 = blockIdx.y * 64;

  // stage E tile -> fp16 LDS, XOR swizzle ((row&7)<<4)
#pragma unroll
  for (int ii = 0; ii < 8; ++ii) {
    int idx = ii * 256 + t;          // f32x4 chunk: row=idx>>5, ck=idx&31
    int row = idx >> 5, ck = idx & 31;
    f32x4 v = ((const f32x4*)(E + (size_t)node0 * 128))[idx];
    *(uint64_t*)(Els + row * 256 + ((ck * 8) ^ ((row & 7) << 4))) = cvt4h(v);
  }
  __syncthreads();

  int lane = t & 63, w = t >> 6;     // 4 waves, each 64M x 32N
  int col = lane & 15, khi = lane >> 4;

  // hoist B fragments: W1fp[q>>1][hb+n][inoff + k]
  const _Float16* Wq = W1fp + (q >> 1) * 65536;
  f16x8 bfr[2][4];
#pragma unroll
  for (int nt = 0; nt < 2; ++nt) {
    int n = w * 32 + nt * 16 + col;
#pragma unroll
    for (int ks = 0; ks < 4; ++ks)
      bfr[nt][ks] = *(const f16x8*)(Wq + (hb + n) * 256 + inoff + ks * 32 + khi * 8);
  }

  f32x4 acc[4][2];
  const f32x4 z = {0.f, 0.f, 0.f, 0.f};
#pragma unroll
  for (int mt = 0; mt < 4; ++mt)
#pragma unroll
    for (int nt = 0; nt < 2; ++nt) acc[mt][nt] = z;

#pragma unroll
  for (int ks = 0; ks < 4; ++ks) {
    f16x8 a[4];
#pragma unroll
    for (int mt = 0; mt < 4; ++mt) {
      int c = mt * 16 + col;
      a[mt] = *(const f16x8*)(Els + c * 256 + ((ks * 64 + khi * 16) ^ ((c & 7) << 4)));
    }
#pragma unroll
    for (int mt = 0; mt < 4; ++mt)
#pragma unroll
      for (int nt = 0; nt < 2; ++nt)
        acc[mt][nt] = __builtin_amdgcn_mfma_f32_16x16x32_f16(a[mt], bfr[nt][ks],
                                                             acc[mt][nt], 0, 0, 0);
  }

  const float* b1q = (q >> 1) ? b1_1 : b1_0;
  float bv[2];
#pragma unroll
  for (int nt = 0; nt < 2; ++nt)
    bv[nt] = (q & 1) ? b1q[hb + w * 32 + nt * 16 + col] : 0.f;

#pragma unroll
  for (int mt = 0; mt < 4; ++mt)
#pragma unroll
    for (int nt = 0; nt < 2; ++nt)
#pragma unroll
      for (int j = 0; j < 4; ++j) {
        int node = node0 + mt * 16 + khi * 4 + j;
        int cgl = q * 256 + hb + w * 32 + nt * 16 + col;
        Tfp[(size_t)node * 1024 + cgl] = (_Float16)(acc[mt][nt][j] + bv[nt]);
      }
}

// Block = (b, 8 r's). 8 waves = 2rg x 2cg x 2dg; wave: 4 r's, 32 c, 64 d.
// Phase p: stage W2_p (64KB LDS, swz), Ts frags in regs; per r: build
// h=relu(ts+tr) in regs (pk f16), MFMA vs W2 from LDS, weight by a/(1-a),
// accumulate per-lane partials. End: shfl-reduce, LDS combine, E update.
__global__ __launch_bounds__(512, 2) void k_edge(const _Float16* __restrict__ Tfp,
                                                 const int* __restrict__ arcs,
                                                 const float* __restrict__ E,
                                                 float* __restrict__ out,
                                                 const _Float16* __restrict__ W2fp,
                                                 const float* __restrict__ b2_0,
                                                 const float* __restrict__ b2_1,
                                                 int last) {
  __shared__ char lds[65536];        // W2 phase buffer; reused as S at end
  int t = threadIdx.x;
  int b = blockIdx.y;
  int rbase = blockIdx.x * 8;
  int lane = t & 63, w = t >> 6;
  int col = lane & 15, khi = lane >> 4;
  int rg = w >> 2, cg = (w >> 1) & 1, dg = w & 1;
  const _Float16* Tb = Tfp + (size_t)b * 64 * 1024;

  float Sreg[4][4];                  // [rr][nt] per-lane partials, both phases
#pragma unroll
  for (int rr = 0; rr < 4; ++rr)
#pragma unroll
    for (int nt = 0; nt < 4; ++nt) Sreg[rr][nt] = 0.f;

#pragma unroll
  for (int p = 0; p < 2; ++p) {
    __syncthreads();                 // phase-0: trivial; phase-1: done reading W2_0
    {
      const u32x4* src = (const u32x4*)W2fp + p * 4096;
#pragma unroll
      for (int ii = 0; ii < 8; ++ii) {
        int cidx = ii * 512 + t;
        int d = cidx >> 5, ck = cidx & 31;
        *(u32x4*)(lds + d * 512 + ((ck * 16) ^ ((d & 7) << 4))) = src[cidx];
      }
    }
    // hoist Ts fragments (global, L2-resident)
    f16x8 ts[2][8];
#pragma unroll
    for (int mt = 0; mt < 2; ++mt) {
      int c = cg * 32 + mt * 16 + col;
#pragma unroll
      for (int ks = 0; ks < 8; ++ks)
        ts[mt][ks] = *(const f16x8*)(Tb + c * 1024 + p * 512 + ks * 32 + khi * 8);
    }
    __syncthreads();                 // W2_p staged

    const float* b2p = p ? b2_1 : b2_0;
    float b2v[4];
#pragma unroll
    for (int nt = 0; nt < 4; ++nt) b2v[nt] = b2p[dg * 64 + nt * 16 + col];

#pragma unroll
    for (int rr = 0; rr < 4; ++rr) {
      int r = rbase + rg * 4 + rr;
      f16x8 tr[8];
#pragma unroll
      for (int ks = 0; ks < 8; ++ks)
        tr[ks] = *(const f16x8*)(Tb + r * 1024 + p * 512 + 256 + ks * 32 + khi * 8);

      f32x4 acc[2][4];
      const f32x4 z = {0.f, 0.f, 0.f, 0.f};
#pragma unroll
      for (int mt = 0; mt < 2; ++mt)
#pragma unroll
        for (int nt = 0; nt < 4; ++nt) acc[mt][nt] = z;

#pragma unroll
      for (int ks = 0; ks < 8; ++ks) {
        f16x8 zv = {};
        f16x8 a[2];
#pragma unroll
        for (int mt = 0; mt < 2; ++mt)
          a[mt] = __builtin_elementwise_max(ts[mt][ks] + tr[ks], zv);
        f16x8 bv[4];
#pragma unroll
        for (int nt = 0; nt < 4; ++nt) {
          int d = dg * 64 + nt * 16 + col;
          bv[nt] = *(const f16x8*)(lds + d * 512 +
                                   ((ks * 64 + khi * 16) ^ ((d & 7) << 4)));
        }
#pragma unroll
        for (int mt = 0; mt < 2; ++mt)
#pragma unroll
          for (int nt = 0; nt < 4; ++nt)
            acc[mt][nt] = __builtin_amdgcn_mfma_f32_16x16x32_f16(a[mt], bv[nt],
                                                                 acc[mt][nt], 0, 0, 0);
      }

      // weight by arc and accumulate
      const int* arow = arcs + ((size_t)(b * 64 + r)) * 64 + cg * 32 + khi * 4;
      int4 ai[2];
#pragma unroll
      for (int mt = 0; mt < 2; ++mt) ai[mt] = *(const int4*)(arow + mt * 16);
#pragma unroll
      for (int mt = 0; mt < 2; ++mt) {
#pragma unroll
        for (int j = 0; j < 4; ++j) {
          int av = (j == 0) ? ai[mt].x : (j == 1) ? ai[mt].y : (j == 2) ? ai[mt].z : ai[mt].w;
          float af = (float)av;
          float wgt = p ? af : 1.0f - af;
#pragma unroll
          for (int nt = 0; nt < 4; ++nt) {
            float m = fmaxf(acc[mt][nt][j] + b2v[nt], 0.f);
            Sreg[rr][nt] = fmaf(wgt, m, Sreg[rr][nt]);
          }
        }
      }
    }
  }

  __syncthreads();                   // done reading W2_1 LDS
  float* S = (float*)lds;            // S[cg][8r][128d] f32 = 8KB
#pragma unroll
  for (int rr = 0; rr < 4; ++rr) {
#pragma unroll
    for (int nt = 0; nt < 4; ++nt) {
      float v = Sreg[rr][nt];
      v += __shfl_xor(v, 16);
      v += __shfl_xor(v, 32);
      Sreg[rr][nt] = v;
    }
    float v = (khi == 0) ? Sreg[rr][0] : (khi == 1) ? Sreg[rr][1]
            : (khi == 2) ? Sreg[rr][2] : Sreg[rr][3];
    int r = rg * 4 + rr;
    S[(cg * 8 + r) * 128 + dg * 64 + khi * 16 + col] = v;
  }
  __syncthreads();

  if (last) {
    if (t < 128)
      out[b * 128 + t] = E[(size_t)b * 64 * 128 + t] + S[t] + S[1024 + t];
  } else {
#pragma unroll
    for (int s = t; s < 1024; s += 512) {
      int r = s >> 7, d = s & 127;
      size_t row = (size_t)b * 64 + rbase + r;
      out[row * 128 + d] = E[row * 128 + d] + S[r * 128 + d] + S[(8 + r) * 128 + d];
    }
  }
}

extern "C" void kernel_launch(void* const* d_in, const int* in_sizes, int n_in,
                              void* d_out, int out_size, void* d_ws, size_t ws_size,
                              hipStream_t stream) {
  const int* x       = (const int*)d_in[0];
  const int* arcs    = (const int*)d_in[1];
  const float* table = (const float*)d_in[3];
  const float* W1_0  = (const float*)d_in[4];
  const float* b1_0  = (const float*)d_in[5];
  const float* W2_0  = (const float*)d_in[6];
  const float* b2_0  = (const float*)d_in[7];
  const float* W1_1  = (const float*)d_in[8];
  const float* b1_1  = (const float*)d_in[9];
  const float* W2_1  = (const float*)d_in[10];
  const float* b2_1  = (const float*)d_in[11];
  float* out = (float*)d_out;

  char* ws = (char*)d_ws;
  float* E         = (float*)ws;                      // 1 MB
  _Float16* Tfp    = (_Float16*)(ws + (1u << 20));    // 4 MB
  _Float16* W1fp   = (_Float16*)(ws + (5u << 20));    // 256 KB
  _Float16* W2fp   = (_Float16*)(ws + (5u << 20) + (256u << 10));  // 128 KB

  k_gather<<<256, 256, 0, stream>>>(x, table, E);
  k_prep<<<192, 256, 0, stream>>>(W1_0, W1_1, W2_0, W2_1, W1fp, W2fp);
  for (int l = 0; l < 3; ++l) {
    int last = (l == 2);
    k_T<<<dim3(8, 32), 256, 0, stream>>>(E, W1fp, b1_0, b1_1, Tfp);
    k_edge<<<dim3(last ? 1 : 8, 32), 512, 0, stream>>>(
        Tfp, arcs, E, last ? out : E, W2fp, b2_0, b2_1, last);
  }
}